// Round 4
// baseline (139.953 us; speedup 1.0000x reference)
//
#include <hip/hip_runtime.h>

#define NJ 22

// 6D continuous rotation -> 3x3 row-major rotation matrix (columns b1,b2,b3)
__device__ __forceinline__ void rot6d_to_mat(float a1x, float a1y, float a1z,
                                             float a2x, float a2y, float a2z,
                                             float* R) {
    float n1 = sqrtf(a1x * a1x + a1y * a1y + a1z * a1z);
    float inv1 = 1.0f / fmaxf(n1, 1e-12f);
    float b1x = a1x * inv1, b1y = a1y * inv1, b1z = a1z * inv1;
    float d = b1x * a2x + b1y * a2y + b1z * a2z;
    float b2x = a2x - b1x * d, b2y = a2y - b1y * d, b2z = a2z - b1z * d;
    float n2 = sqrtf(b2x * b2x + b2y * b2y + b2z * b2z);
    float inv2 = 1.0f / fmaxf(n2, 1e-12f);
    b2x *= inv2; b2y *= inv2; b2z *= inv2;
    float b3x = b1y * b2z - b1z * b2y;
    float b3y = b1z * b2x - b1x * b2z;
    float b3z = b1x * b2y - b1y * b2x;
    // columns are b1, b2, b3
    R[0] = b1x; R[1] = b2x; R[2] = b3x;
    R[3] = b1y; R[4] = b2y; R[5] = b3y;
    R[6] = b1z; R[7] = b2z; R[8] = b3z;
}

__device__ __forceinline__ void matmul3(const float* __restrict__ A,
                                        const float* __restrict__ B,
                                        float* __restrict__ C) {
#pragma unroll
    for (int r = 0; r < 3; ++r) {
#pragma unroll
        for (int c = 0; c < 3; ++c) {
            C[r * 3 + c] = A[r * 3 + 0] * B[0 * 3 + c]
                         + A[r * 3 + 1] * B[1 * 3 + c]
                         + A[r * 3 + 2] * B[2 * 3 + c];
        }
    }
}

__global__ __launch_bounds__(256) void mpjpe_fk_kernel(
    const float* __restrict__ pred_pos,   // [NP, 20, 3]
    const float* __restrict__ gt_rot,     // [NP, 22, 6]
    const float* __restrict__ offsets,    // [22, 3]
    float* __restrict__ out,              // [1]
    int nposes, float scale)              // scale = 1000 / (NP*20)
{
    constexpr int PAR[NJ] = {-1, 0, 0, 0, 1, 2, 3, 4, 5, 6, 7, 8, 9, 9, 9, 12, 13, 14, 16, 17, 18, 19};

    int t = blockIdx.x * blockDim.x + threadIdx.x;
    float sum = 0.0f;

    if (t < nposes) {
        const float* gr = gt_rot + (size_t)t * (NJ * 6);
        const float* pp = pred_pos + (size_t)t * (20 * 3);

        float R[NJ][9];
        float P[NJ][3];

        // joint 0: identity rotation, zero position
        R[0][0] = 1.f; R[0][1] = 0.f; R[0][2] = 0.f;
        R[0][3] = 0.f; R[0][4] = 1.f; R[0][5] = 0.f;
        R[0][6] = 0.f; R[0][7] = 0.f; R[0][8] = 1.f;
        P[0][0] = 0.f; P[0][1] = 0.f; P[0][2] = 0.f;

#pragma unroll
        for (int i = 1; i < NJ; ++i) {
            const int p = PAR[i];
            // position: P[i] = P[p] + R[p] @ offsets[i]
            float ox = offsets[i * 3 + 0];
            float oy = offsets[i * 3 + 1];
            float oz = offsets[i * 3 + 2];
#pragma unroll
            for (int r = 0; r < 3; ++r) {
                P[i][r] = P[p][r] + R[p][r * 3 + 0] * ox
                                  + R[p][r * 3 + 1] * oy
                                  + R[p][r * 3 + 2] * oz;
            }
            // rotation: R[i] = R[p] @ local (local = I for joint 1)
            if (i == 1) {
#pragma unroll
                for (int k = 0; k < 9; ++k) R[i][k] = R[p][k];
            } else {
                // 6D record at 24B stride -> 8B aligned: three float2 loads
                const float2* g2 = (const float2*)(gr + i * 6);
                float2 v0 = g2[0], v1 = g2[1], v2 = g2[2];
                float M[9];
                rot6d_to_mat(v0.x, v0.y, v1.x, v1.y, v2.x, v2.y, M);
                matmul3(R[p], M, R[i]);
            }
            // distance vs prediction (joints 2..21 -> pred index i-2)
            if (i >= 2) {
                float dx = pp[(i - 2) * 3 + 0] - P[i][0];
                float dy = pp[(i - 2) * 3 + 1] - P[i][1];
                float dz = pp[(i - 2) * 3 + 2] - P[i][2];
                sum += sqrtf(dx * dx + dy * dy + dz * dz);
            }
        }
    }

    // wave (64-lane) reduction
#pragma unroll
    for (int o = 32; o > 0; o >>= 1) sum += __shfl_down(sum, o, 64);

    __shared__ float ws[4];
    int lane = threadIdx.x & 63;
    int wid = threadIdx.x >> 6;
    if (lane == 0) ws[wid] = sum;
    __syncthreads();
    if (threadIdx.x == 0) {
        float s = ws[0] + ws[1] + ws[2] + ws[3];
        atomicAdd(out, s * scale);
    }
}

extern "C" void kernel_launch(void* const* d_in, const int* in_sizes, int n_in,
                              void* d_out, int out_size, void* d_ws, size_t ws_size,
                              hipStream_t stream) {
    const float* pred_pos = (const float*)d_in[0];
    const float* gt_rot   = (const float*)d_in[1];
    const float* offsets  = (const float*)d_in[2];
    float* out = (float*)d_out;

    int nposes = in_sizes[1] / (NJ * 6);   // B*S
    float scale = 1000.0f / ((float)nposes * 20.0f);

    hipMemsetAsync(out, 0, sizeof(float), stream);

    int block = 256;
    int grid = (nposes + block - 1) / block;
    mpjpe_fk_kernel<<<grid, block, 0, stream>>>(pred_pos, gt_rot, offsets, out, nposes, scale);
}